// Round 4
// baseline (783.442 us; speedup 1.0000x reference)
//
#include <hip/hip_runtime.h>
#include <hip/hip_bf16.h>

#define NE      4
#define DIM     2048      // model dim: K of gemm1, N of gemm2
#define FF      2048      // per-expert hidden: N of gemm1, K of gemm2
#define NTOK    16384
#define VOCABSZ 100000
#define TPE     (VOCABSZ / NE)
#define SLICE   ((size_t)NE * FF * DIM)   // 16,777,216 elems = 32 MiB bf16
#define NYT     68                        // max 256-row tiles over all experts

typedef __attribute__((ext_vector_type(8))) short bf16x8;
typedef __attribute__((ext_vector_type(4))) float f32x4;

#define GPTR(p) ((const __attribute__((address_space(1))) void*)(p))
#define LPTR(p) ((__attribute__((address_space(3))) void*)(p))
#define MFMA    __builtin_amdgcn_mfma_f32_16x16x32_bf16
#define GLL(g, l) __builtin_amdgcn_global_load_lds(GPTR(g), LPTR(l), 16, 0, 0)

__device__ __forceinline__ unsigned short f2bf(float f) {
  unsigned u = __builtin_bit_cast(unsigned, f);
  u += 0x7fffu + ((u >> 16) & 1u);          // RNE
  return (unsigned short)(u >> 16);
}

__device__ __forceinline__ bf16x8 pack8(float4 a, float4 b) {
  bf16x8 r;
  r[0] = (short)f2bf(a.x); r[1] = (short)f2bf(a.y);
  r[2] = (short)f2bf(a.z); r[3] = (short)f2bf(a.w);
  r[4] = (short)f2bf(b.x); r[5] = (short)f2bf(b.y);
  r[6] = (short)f2bf(b.z); r[7] = (short)f2bf(b.w);
  return r;
}

// meta: [0..3]=counts [4..7]=cursors [8..11]=offsets [12]=ntiles(256)
__global__ void k_init(int* meta) { if (threadIdx.x < 16) meta[threadIdx.x] = 0; }

__global__ void k_assign(const int* __restrict__ tok, int* __restrict__ eid,
                         int* __restrict__ meta) {
  int i = blockIdx.x * 256 + threadIdx.x;
  int t = tok[i];
  t = t < 0 ? 0 : (t >= VOCABSZ ? VOCABSZ - 1 : t);
  int e = t / TPE; if (e > NE - 1) e = NE - 1;
  eid[i] = e;
  atomicAdd(&meta[e], 1);
}

__global__ void k_prefix(int* meta, int* tlist) {
  if (threadIdx.x == 0 && blockIdx.x == 0) {
    int s = 0, n = 0;
    for (int e = 0; e < NE; ++e) {
      meta[8 + e] = s;
      int c = meta[e]; s += c;
      for (int m = 0; m * 256 < c; ++m) tlist[n++] = (e << 16) | m;
    }
    meta[12] = n;
  }
}

__global__ void k_scatter(const int* __restrict__ eid, int* __restrict__ meta,
                          int* __restrict__ perm) {
  int i = blockIdx.x * 256 + threadIdx.x;
  int e = eid[i];
  int pos = meta[8 + e] + atomicAdd(&meta[4 + e], 1);
  perm[pos] = i;
}

// cast Wg, Wu, Wd, X (5 x SLICE fp32) -> contiguous bf16
__global__ void k_cast5(const float* __restrict__ wg, const float* __restrict__ wu,
                        const float* __restrict__ wd, const float* __restrict__ x,
                        unsigned short* __restrict__ dst) {
  int y = blockIdx.y;
  const float* s;
  if (y == 0) s = wg; else if (y == 1) s = wu; else if (y == 2) s = wd;
  else if (y == 3) s = x; else s = x + SLICE;
  unsigned short* d = dst + (size_t)y * SLICE;
  size_t i = ((size_t)blockIdx.x * 256 + threadIdx.x) * 8;
  float4 a = *(const float4*)(s + i);
  float4 b = *(const float4*)(s + i + 4);
  *(bf16x8*)(d + i) = pack8(a, b);
}

// ---------------- GEMM1: Hb = silu(X Wg^T) * (X Wu^T)
// BM=256, dual-B 128(g)+128(u), BK=64, 8 waves (2M x 4N)
// 4-phase/K-tile interleave (T3+T4), setprio (T5), counted-vmcnt prefetch
__global__ __launch_bounds__(512, 2) void k_gemm1(
    const unsigned short* __restrict__ Xb,
    const unsigned short* __restrict__ Wgb,
    const unsigned short* __restrict__ Wub,
    const int* __restrict__ meta,
    const int* __restrict__ perm,
    const int* __restrict__ tlist,
    unsigned short* __restrict__ Hb)
{
  // XCD-aware remap (NWG = 16*NYT, %8==0)
  int L = blockIdx.y * gridDim.x + blockIdx.x;
  int NWG = gridDim.x * gridDim.y;
  int logical = (L & 7) * (NWG >> 3) + (L >> 3);
  int nt = logical / NYT;
  int ti = logical % NYT;
  if (ti >= meta[12]) return;
  int pk = tlist[ti];
  int e = pk >> 16, mt = pk & 0xffff;
  int cnt = meta[e], base = meta[8 + e];
  int mrows = cnt - mt * 256; if (mrows > 256) mrows = 256;

  // per buffer 64KB: A[256][64] @0, Bg[128][64] @32768, Bu[128][64] @49152
  __shared__ __align__(16) char smem[131072];

  int t = threadIdx.x, lane = t & 63, wid = t >> 6;
  int wm = wid >> 2, wn = wid & 3;

  int rsub = t >> 3;                          // 0..63
  int swb = ((t & 7) ^ (rsub & 7)) * 8;       // pre-swizzled 16B slot (elems)
  const unsigned short* asrc[4];
  #pragma unroll
  for (int l = 0; l < 4; ++l) {
    int gr = mt * 256 + l * 64 + rsub; if (gr >= cnt) gr = cnt - 1;
    asrc[l] = Xb + (size_t)perm[base + gr] * DIM + swb;
  }
  const unsigned short* gsrc[2];
  const unsigned short* usrc[2];
  #pragma unroll
  for (int l = 0; l < 2; ++l) {
    size_t wrow = (size_t)e * FF * DIM + (size_t)(nt * 128 + l * 64 + rsub) * DIM + swb;
    gsrc[l] = Wgb + wrow;
    usrc[l] = Wub + wrow;
  }

  int fr = lane & 15, fc = lane >> 4, sx = fr & 7, fq = lane >> 4;
  int aoff[8], goff[2];
  #pragma unroll
  for (int m = 0; m < 8; ++m) aoff[m] = (wm * 128 + m * 16 + fr) * 128;
  #pragma unroll
  for (int n = 0; n < 2; ++n) goff[n] = (wn * 32 + n * 16 + fr) * 128;

  f32x4 accg[8][2] = {};
  f32x4 accu[8][2] = {};

  // prologue: stage tile 0 into buf 0
  {
    char* bb = smem + wid * 1024;
    GLL(asrc[0], bb);            GLL(asrc[1], bb + 8192);
    GLL(asrc[2], bb + 16384);    GLL(asrc[3], bb + 24576);
    GLL(gsrc[0], bb + 32768);    GLL(gsrc[1], bb + 40960);
    GLL(usrc[0], bb + 49152);    GLL(usrc[1], bb + 57344);
  }
  asm volatile("s_waitcnt vmcnt(0)" ::: "memory");
  __builtin_amdgcn_s_barrier();

  const int NT2 = DIM / 64;    // 32
  for (int kt = 0; kt < NT2; ++kt) {
    int b = kt & 1;
    const char* Ab = smem + b * 65536;
    const char* Gb = Ab + 32768;
    const char* Ub = Ab + 49152;
    char* nbb = smem + (b ^ 1) * 65536 + wid * 1024;
    int pf = (kt + 1 < NT2);
    int k0n = (kt + 1) * 64;

    #pragma unroll
    for (int kk = 0; kk < 2; ++kk) {
      int so = ((kk * 4 + fc) ^ sx) * 16;
      bf16x8 g0, g1, u0, u1;
      #pragma unroll
      for (int mh = 0; mh < 2; ++mh) {
        bf16x8 af[4];
        #pragma unroll
        for (int m = 0; m < 4; ++m)
          af[m] = *(const bf16x8*)(Ab + aoff[mh * 4 + m] + so);
        if (mh == 0) {
          g0 = *(const bf16x8*)(Gb + goff[0] + so);
          g1 = *(const bf16x8*)(Gb + goff[1] + so);
          u0 = *(const bf16x8*)(Ub + goff[0] + so);
          u1 = *(const bf16x8*)(Ub + goff[1] + so);
        }
        if (pf && kk == 0) {
          if (mh == 0) {
            GLL(asrc[0] + k0n, nbb);            GLL(asrc[1] + k0n, nbb + 8192);
            GLL(asrc[2] + k0n, nbb + 16384);    GLL(asrc[3] + k0n, nbb + 24576);
          } else {
            GLL(gsrc[0] + k0n, nbb + 32768);    GLL(gsrc[1] + k0n, nbb + 40960);
            GLL(usrc[0] + k0n, nbb + 49152);    GLL(usrc[1] + k0n, nbb + 57344);
          }
        }
        __builtin_amdgcn_s_barrier();
        asm volatile("s_waitcnt lgkmcnt(0)" ::: "memory");
        __builtin_amdgcn_sched_barrier(0);
        __builtin_amdgcn_s_setprio(1);
        #pragma unroll
        for (int m = 0; m < 4; ++m) {
          int mi = mh * 4 + m;
          accg[mi][0] = MFMA(af[m], g0, accg[mi][0], 0, 0, 0);
          accg[mi][1] = MFMA(af[m], g1, accg[mi][1], 0, 0, 0);
          accu[mi][0] = MFMA(af[m], u0, accu[mi][0], 0, 0, 0);
          accu[mi][1] = MFMA(af[m], u1, accu[mi][1], 0, 0, 0);
        }
        __builtin_amdgcn_s_setprio(0);
        if (kk == 1 && mh == 1)
          asm volatile("s_waitcnt vmcnt(0)" ::: "memory");
        __builtin_amdgcn_s_barrier();
      }
    }
  }

  #pragma unroll
  for (int m = 0; m < 8; ++m) {
    #pragma unroll
    for (int v = 0; v < 4; ++v) {
      int rl = wm * 128 + m * 16 + fq * 4 + v;
      if (rl < mrows) {
        size_t ro = (size_t)(base + mt * 256 + rl) * FF + nt * 128 + wn * 32 + fr;
        float g0 = accg[m][0][v], uu0 = accu[m][0][v];
        float g1 = accg[m][1][v], uu1 = accu[m][1][v];
        Hb[ro]      = f2bf(g0 / (1.0f + __expf(-g0)) * uu0);
        Hb[ro + 16] = f2bf(g1 / (1.0f + __expf(-g1)) * uu1);
      }
    }
  }
}

// ---------------- GEMM2: Out[perm[row]] = Hb Wd^T   (BM=BN=256, BK=64)
__global__ __launch_bounds__(512, 2) void k_gemm2(
    const unsigned short* __restrict__ Hb,
    const unsigned short* __restrict__ Wdb,
    const int* __restrict__ meta,
    const int* __restrict__ perm,
    const int* __restrict__ tlist,
    float* __restrict__ Out)
{
  int L = blockIdx.y * gridDim.x + blockIdx.x;
  int NWG = gridDim.x * gridDim.y;
  int logical = (L & 7) * (NWG >> 3) + (L >> 3);
  int nt = logical / NYT;
  int ti = logical % NYT;
  if (ti >= meta[12]) return;
  int pk = tlist[ti];
  int e = pk >> 16, mt = pk & 0xffff;
  int cnt = meta[e], base = meta[8 + e];
  int mrows = cnt - mt * 256; if (mrows > 256) mrows = 256;

  // per buffer 64KB: A[256][64] @0, B[256][64] @32768
  __shared__ __align__(16) char smem[131072];

  int t = threadIdx.x, lane = t & 63, wid = t >> 6;
  int wm = wid >> 2, wn = wid & 3;

  int rsub = t >> 3;
  int swb = ((t & 7) ^ (rsub & 7)) * 8;
  const unsigned short* asrc[4];
  const unsigned short* bsrc[4];
  #pragma unroll
  for (int l = 0; l < 4; ++l) {
    int gr = mt * 256 + l * 64 + rsub; if (gr >= cnt) gr = cnt - 1;
    asrc[l] = Hb + (size_t)(base + gr) * FF + swb;
    bsrc[l] = Wdb + (size_t)e * DIM * FF + (size_t)(nt * 256 + l * 64 + rsub) * FF + swb;
  }

  int fr = lane & 15, fc = lane >> 4, sx = fr & 7, fq = lane >> 4;
  int aoff[8], boff[4];
  #pragma unroll
  for (int m = 0; m < 8; ++m) aoff[m] = (wm * 128 + m * 16 + fr) * 128;
  #pragma unroll
  for (int n = 0; n < 4; ++n) boff[n] = (wn * 64 + n * 16 + fr) * 128;

  f32x4 acc[8][4] = {};

  {
    char* bb = smem + wid * 1024;
    GLL(asrc[0], bb);            GLL(asrc[1], bb + 8192);
    GLL(asrc[2], bb + 16384);    GLL(asrc[3], bb + 24576);
    GLL(bsrc[0], bb + 32768);    GLL(bsrc[1], bb + 40960);
    GLL(bsrc[2], bb + 49152);    GLL(bsrc[3], bb + 57344);
  }
  asm volatile("s_waitcnt vmcnt(0)" ::: "memory");
  __builtin_amdgcn_s_barrier();

  const int NT2 = FF / 64;     // 32
  for (int kt = 0; kt < NT2; ++kt) {
    int b = kt & 1;
    const char* Ab = smem + b * 65536;
    const char* Bb = Ab + 32768;
    char* nbb = smem + (b ^ 1) * 65536 + wid * 1024;
    int pf = (kt + 1 < NT2);
    int k0n = (kt + 1) * 64;

    #pragma unroll
    for (int kk = 0; kk < 2; ++kk) {
      int so = ((kk * 4 + fc) ^ sx) * 16;
      bf16x8 bfr[4];
      #pragma unroll
      for (int mh = 0; mh < 2; ++mh) {
        bf16x8 af[4];
        #pragma unroll
        for (int m = 0; m < 4; ++m)
          af[m] = *(const bf16x8*)(Ab + aoff[mh * 4 + m] + so);
        if (mh == 0) {
          #pragma unroll
          for (int n = 0; n < 4; ++n)
            bfr[n] = *(const bf16x8*)(Bb + boff[n] + so);
        }
        if (pf && kk == 0) {
          if (mh == 0) {
            GLL(asrc[0] + k0n, nbb);            GLL(asrc[1] + k0n, nbb + 8192);
            GLL(asrc[2] + k0n, nbb + 16384);    GLL(asrc[3] + k0n, nbb + 24576);
          } else {
            GLL(bsrc[0] + k0n, nbb + 32768);    GLL(bsrc[1] + k0n, nbb + 40960);
            GLL(bsrc[2] + k0n, nbb + 49152);    GLL(bsrc[3] + k0n, nbb + 57344);
          }
        }
        __builtin_amdgcn_s_barrier();
        asm volatile("s_waitcnt lgkmcnt(0)" ::: "memory");
        __builtin_amdgcn_sched_barrier(0);
        __builtin_amdgcn_s_setprio(1);
        #pragma unroll
        for (int m = 0; m < 4; ++m) {
          #pragma unroll
          for (int n = 0; n < 4; ++n)
            acc[mh * 4 + m][n] = MFMA(af[m], bfr[n], acc[mh * 4 + m][n], 0, 0, 0);
        }
        __builtin_amdgcn_s_setprio(0);
        if (kk == 1 && mh == 1)
          asm volatile("s_waitcnt vmcnt(0)" ::: "memory");
        __builtin_amdgcn_s_barrier();
      }
    }
  }

  #pragma unroll
  for (int m = 0; m < 8; ++m) {
    #pragma unroll
    for (int v = 0; v < 4; ++v) {
      int rl = wm * 128 + m * 16 + fq * 4 + v;
      if (rl < mrows) {
        int tok = perm[base + mt * 256 + rl];
        float* o = Out + (size_t)tok * DIM + nt * 256 + wn * 64 + fr;
        #pragma unroll
        for (int n = 0; n < 4; ++n)
          o[n * 16] = acc[m][n][v];
      }
    }
  }
}

extern "C" void kernel_launch(void* const* d_in, const int* in_sizes, int n_in,
                              void* d_out, int out_size, void* d_ws, size_t ws_size,
                              hipStream_t stream) {
  (void)in_sizes; (void)n_in; (void)out_size; (void)ws_size;
  const float* X   = (const float*)d_in[0];
  const int*   tok = (const int*)d_in[1];
  const float* Wg  = (const float*)d_in[2];
  const float* Wu  = (const float*)d_in[3];
  const float* Wd  = (const float*)d_in[4];
  float* Out = (float*)d_out;

  char* ws = (char*)d_ws;
  int* meta  = (int*)ws;                      // 16 ints
  int* tlist = (int*)(ws + 64);               // up to ~68 tiles
  int* eid   = (int*)(ws + 2048);             // 16384 ints
  int* perm  = (int*)(ws + 2048 + 65536);     // 16384 ints
  unsigned short* Wbf  = (unsigned short*)(ws + 133120);
  unsigned short* WgBf = Wbf;
  unsigned short* WuBf = Wbf + SLICE;
  unsigned short* WdBf = Wbf + 2 * SLICE;
  unsigned short* Xbf  = Wbf + 3 * SLICE;     // 2 slices (NTOK*DIM)
  unsigned short* Hb   = Wbf + 5 * SLICE;     // NTOK*FF
  // total ws use: 133120 + 5*33554432 + 67108864 = 235,014,144 bytes (~224 MiB)

  k_init   <<<1, 64, 0, stream>>>(meta);
  k_assign <<<NTOK / 256, 256, 0, stream>>>(tok, eid, meta);
  k_prefix <<<1, 64, 0, stream>>>(meta, tlist);
  k_scatter<<<NTOK / 256, 256, 0, stream>>>(eid, meta, perm);
  k_cast5  <<<dim3((unsigned)(SLICE / 2048), 5), 256, 0, stream>>>(Wg, Wu, Wd, X, Wbf);
  k_gemm1  <<<dim3(FF / 128, NYT), 512, 0, stream>>>(Xbf, WgBf, WuBf, meta, perm, tlist, Hb);
  k_gemm2  <<<dim3(DIM / 256, NYT), 512, 0, stream>>>(Hb, WdBf, meta, perm, tlist, Out);
}